// Round 2
// baseline (1316.423 us; speedup 1.0000x reference)
//
#include <hip/hip_runtime.h>

#define NN 100000
#define DD 128
#define EE 640000

typedef __bf16 bf16x8 __attribute__((ext_vector_type(8)));
typedef float floatx4 __attribute__((ext_vector_type(4)));

__device__ __forceinline__ unsigned short f2bf(float f) {
    unsigned int u = __float_as_uint(f);
    u += 0x7FFF + ((u >> 16) & 1);   // round-to-nearest-even
    return (unsigned short)(u >> 16);
}

// ---------------------------------------------------------------------------
// 1) scatter-add: aggr[dst] += x[src], 32 lanes per edge, float4 per lane
//    NOTE: harness passes integer inputs as int32 (NOT the reference's int64)
// ---------------------------------------------------------------------------
__global__ __launch_bounds__(256) void scatter_add_k(
    const float4* __restrict__ x4, const int* __restrict__ ei,
    float* __restrict__ aggr) {
    int tid = blockIdx.x * 256 + threadIdx.x;
    int e = tid >> 5, lane = tid & 31;
    if (e >= EE) return;
    int src = ei[e];
    int dst = ei[EE + e];
    float4 v = x4[src * 32 + lane];
    float* p = aggr + dst * 128 + lane * 4;
    unsafeAtomicAdd(p + 0, v.x);
    unsafeAtomicAdd(p + 1, v.y);
    unsafeAtomicAdd(p + 2, v.z);
    unsafeAtomicAdd(p + 3, v.w);
}

// ---------------------------------------------------------------------------
// 2) fused GEMM + bias + BN-stat accumulation
//    MODE 0: in = (1+eps)*x + aggr (fp32 -> bf16)   MODE 1: in = h1 (bf16)
//    y = in @ W^T + b  (fp32 out), stats[c] += sum_col, stats[128+c] += sumsq
// ---------------------------------------------------------------------------
template <int MODE>
__global__ __launch_bounds__(256, 2) void gin_gemm_k(
    const float* __restrict__ x, const float* __restrict__ aggr,
    const unsigned short* __restrict__ hin,
    const float* __restrict__ W, const float* __restrict__ bias,
    const float* __restrict__ epsp,
    float* __restrict__ y, float* __restrict__ stats) {
    __shared__ __align__(16) unsigned short Ah[128][136];  // +8 pad: 2-way LDS (free)
    __shared__ __align__(16) unsigned short Bw[128][136];
    __shared__ __align__(16) float s_sum[128];
    __shared__ __align__(16) float s_sq[128];

    const int tid = threadIdx.x;
    const int rowBase = blockIdx.x * 128;

    if (tid < 128) { s_sum[tid] = 0.f; s_sq[tid] = 0.f; }

    // stage W (row-major [out][k]) -> Bw bf16; B[k][n] = W[n][k] so Bw row n = W row n
    const float4* W4 = (const float4*)W;
#pragma unroll
    for (int j = 0; j < 16; ++j) {
        int f4 = j * 256 + tid;
        int row = f4 >> 5, k4 = f4 & 31;
        float4 wv = W4[f4];
        ushort4 u;
        u.x = f2bf(wv.x); u.y = f2bf(wv.y); u.z = f2bf(wv.z); u.w = f2bf(wv.w);
        *(ushort4*)&Bw[row][k4 * 4] = u;
    }

    if (MODE == 0) {
        const float ef = 1.0f + epsp[0];
        const float4* x4 = (const float4*)x;
        const float4* a4 = (const float4*)aggr;
#pragma unroll
        for (int j = 0; j < 16; ++j) {
            int f4 = j * 256 + tid;
            int row = f4 >> 5, k4 = f4 & 31;
            int rg = rowBase + row;
            ushort4 u = make_ushort4(0, 0, 0, 0);
            if (rg < NN) {
                float4 xv = x4[rg * 32 + k4];
                float4 av = a4[rg * 32 + k4];
                u.x = f2bf(ef * xv.x + av.x);
                u.y = f2bf(ef * xv.y + av.y);
                u.z = f2bf(ef * xv.z + av.z);
                u.w = f2bf(ef * xv.w + av.w);
            }
            *(ushort4*)&Ah[row][k4 * 4] = u;
        }
    } else {
        const int4* h16 = (const int4*)hin;
#pragma unroll
        for (int j = 0; j < 8; ++j) {
            int c = j * 256 + tid;
            int row = c >> 4, c8 = c & 15;
            int rg = rowBase + row;
            int4 v = make_int4(0, 0, 0, 0);
            if (rg < NN) v = h16[rg * 16 + c8];
            *(int4*)&Ah[row][c8 * 8] = v;
        }
    }

    __syncthreads();

    const int l = tid & 63, w = tid >> 6;
    const int m = l & 15, q = l >> 4;

    floatx4 acc[2][8];
#pragma unroll
    for (int rt = 0; rt < 2; ++rt)
#pragma unroll
        for (int ct = 0; ct < 8; ++ct) acc[rt][ct] = (floatx4)0.0f;

#pragma unroll
    for (int kc = 0; kc < 4; ++kc) {
        int k0 = kc * 32 + q * 8;
        bf16x8 a0 = *(const bf16x8*)&Ah[w * 32 + m][k0];
        bf16x8 a1 = *(const bf16x8*)&Ah[w * 32 + 16 + m][k0];
#pragma unroll
        for (int ct = 0; ct < 8; ++ct) {
            bf16x8 b = *(const bf16x8*)&Bw[ct * 16 + m][k0];
            acc[0][ct] = __builtin_amdgcn_mfma_f32_16x16x32_bf16(a0, b, acc[0][ct], 0, 0, 0);
            acc[1][ct] = __builtin_amdgcn_mfma_f32_16x16x32_bf16(a1, b, acc[1][ct], 0, 0, 0);
        }
    }

    // epilogue: bias, store y, per-column partial stats (mask padding rows!)
#pragma unroll
    for (int ct = 0; ct < 8; ++ct) {
        int col = ct * 16 + m;
        float bc = bias[col];
        float ps = 0.f, pq = 0.f;
#pragma unroll
        for (int rt = 0; rt < 2; ++rt) {
#pragma unroll
            for (int i = 0; i < 4; ++i) {
                int rg = rowBase + w * 32 + rt * 16 + q * 4 + i;
                if (rg < NN) {
                    float yv = acc[rt][ct][i] + bc;
                    y[rg * 128 + col] = yv;
                    ps += yv;
                    pq += yv * yv;
                }
            }
        }
        atomicAdd(&s_sum[col], ps);
        atomicAdd(&s_sq[col], pq);
    }
    __syncthreads();
    if (tid < 128) {
        unsafeAtomicAdd(&stats[tid], s_sum[tid]);
        unsafeAtomicAdd(&stats[128 + tid], s_sq[tid]);
    }
}

// ---------------------------------------------------------------------------
// 3) BN(train-mode, biased var) + ReLU apply.  OUT_BF16: write bf16 (h1) else
//    fp32 (may alias y in-place: pure elementwise, same index)
// ---------------------------------------------------------------------------
template <int OUT_BF16>
__global__ __launch_bounds__(256) void bn_relu_k(
    const float* __restrict__ y, const float* __restrict__ stats,
    const float* __restrict__ g, const float* __restrict__ beta,
    float* outf, unsigned short* __restrict__ outh) {
    __shared__ __align__(16) float sc[128];
    __shared__ __align__(16) float sh[128];
    int t = threadIdx.x;
    if (t < 128) {
        const float inv = 1.0f / (float)NN;
        float mean = stats[t] * inv;
        float var = stats[128 + t] * inv - mean * mean;
        float s = g[t] * rsqrtf(var + 1e-5f);
        sc[t] = s;
        sh[t] = beta[t] - mean * s;
    }
    __syncthreads();
    const int total4 = NN * 32;
    const float4* y4 = (const float4*)y;
    for (int i = blockIdx.x * 256 + t; i < total4; i += gridDim.x * 256) {
        int c4 = i & 31;
        float4 v = y4[i];
        float4 s = ((const float4*)sc)[c4];
        float4 b = ((const float4*)sh)[c4];
        float r0 = fmaxf(v.x * s.x + b.x, 0.f);
        float r1 = fmaxf(v.y * s.y + b.y, 0.f);
        float r2 = fmaxf(v.z * s.z + b.z, 0.f);
        float r3 = fmaxf(v.w * s.w + b.w, 0.f);
        if (OUT_BF16) {
            ushort4 u;
            u.x = f2bf(r0); u.y = f2bf(r1); u.z = f2bf(r2); u.w = f2bf(r3);
            ((ushort4*)outh)[i] = u;
        } else {
            ((float4*)outf)[i] = make_float4(r0, r1, r2, r3);
        }
    }
}

// ---------------------------------------------------------------------------
extern "C" void kernel_launch(void* const* d_in, const int* in_sizes, int n_in,
                              void* d_out, int out_size, void* d_ws, size_t ws_size,
                              hipStream_t stream) {
    const float* x   = (const float*)d_in[0];
    const int* ei    = (const int*)d_in[1];   // int64 in ref -> int32 from harness
    const float* eps = (const float*)d_in[2];
    const float* W1  = (const float*)d_in[3];
    const float* b1  = (const float*)d_in[4];
    const float* g1  = (const float*)d_in[5];
    const float* be1 = (const float*)d_in[6];
    const float* W2  = (const float*)d_in[7];
    const float* b2  = (const float*)d_in[8];
    const float* g2  = (const float*)d_in[9];
    const float* be2 = (const float*)d_in[10];
    float* out = (float*)d_out;

    // Workspace layout (keep small; ws_size unknown):
    //   bufA: N*D fp32 = 51.2 MB  (aggr; later reused as bf16 h1 = 25.6 MB)
    //   stats: 512 fp32
    // GEMM outputs y1/y2 live in d_out (y1 fully consumed before y2 written;
    // final BN+ReLU is elementwise in-place on d_out).
    const size_t bufElems = (size_t)NN * DD;
    float* bufA  = (float*)d_ws;
    float* stats = bufA + bufElems;

    hipMemsetAsync(bufA, 0, bufElems * sizeof(float), stream);
    hipMemsetAsync(stats, 0, 512 * sizeof(float), stream);

    scatter_add_k<<<EE * 32 / 256, 256, 0, stream>>>((const float4*)x, ei, bufA);

    int gblocks = (NN + 127) / 128;  // 782
    gin_gemm_k<0><<<gblocks, 256, 0, stream>>>(x, bufA, nullptr, W1, b1, eps,
                                               out, stats);
    bn_relu_k<1><<<4096, 256, 0, stream>>>(out, stats, g1, be1, nullptr,
                                           (unsigned short*)bufA);
    gin_gemm_k<1><<<gblocks, 256, 0, stream>>>(nullptr, nullptr,
                                               (const unsigned short*)bufA, W2,
                                               b2, eps, out, stats + 256);
    bn_relu_k<0><<<4096, 256, 0, stream>>>(out, stats + 256, g2, be2, out,
                                           nullptr);
}

// Round 3
// 359.818 us; speedup vs baseline: 3.6586x; 3.6586x over previous
//
#include <hip/hip_runtime.h>

#define NN 100000
#define DD 128
#define EE 640000
#define NPAD 100352  // NN rounded up to 256 multiple

typedef __bf16 bf16x8 __attribute__((ext_vector_type(8)));
typedef float floatx4 __attribute__((ext_vector_type(4)));

__device__ __forceinline__ unsigned short f2bf(float f) {
    unsigned int u = __float_as_uint(f);
    u += 0x7FFF + ((u >> 16) & 1);   // round-to-nearest-even
    return (unsigned short)(u >> 16);
}

// ---------------------------------------------------------------------------
// CSR build: histogram -> 3-kernel exclusive scan -> bucket scatter
// ---------------------------------------------------------------------------
__global__ __launch_bounds__(256) void hist_k(const int* __restrict__ ei,
                                              int* __restrict__ deg) {
    int e = blockIdx.x * 256 + threadIdx.x;
    if (e < EE) atomicAdd(&deg[ei[EE + e]], 1);
}

__global__ __launch_bounds__(256) void scan1_k(const int* __restrict__ deg,
                                               int* __restrict__ exc,
                                               int* __restrict__ chunkSums) {
    __shared__ int s[256];
    int t = threadIdx.x, g = blockIdx.x * 256 + t;
    int v = (g < NN) ? deg[g] : 0;
    s[t] = v;
    __syncthreads();
    for (int off = 1; off < 256; off <<= 1) {
        int u = (t >= off) ? s[t - off] : 0;
        __syncthreads();
        s[t] += u;
        __syncthreads();
    }
    if (g < NN) exc[g] = s[t] - v;
    if (t == 255) chunkSums[blockIdx.x] = s[255];
}

__global__ __launch_bounds__(512) void scan2_k(int* __restrict__ chunkSums, int n) {
    __shared__ int s[512];
    int t = threadIdx.x;
    int v = (t < n) ? chunkSums[t] : 0;
    s[t] = v;
    __syncthreads();
    for (int off = 1; off < 512; off <<= 1) {
        int u = (t >= off) ? s[t - off] : 0;
        __syncthreads();
        s[t] += u;
        __syncthreads();
    }
    if (t < n) chunkSums[t] = s[t] - v;  // exclusive
}

__global__ __launch_bounds__(256) void scan3_k(int* __restrict__ exc,
                                               const int* __restrict__ chunkSums,
                                               int* __restrict__ cursor) {
    int g = blockIdx.x * 256 + threadIdx.x;
    if (g < NN) {
        int o = exc[g] + chunkSums[blockIdx.x];
        exc[g] = o;
        cursor[g] = o;
    }
}

__global__ __launch_bounds__(256) void esort_k(const int* __restrict__ ei,
                                               int* __restrict__ cursor,
                                               int* __restrict__ ssrc) {
    int e = blockIdx.x * 256 + threadIdx.x;
    if (e >= EE) return;
    int pos = atomicAdd(&cursor[ei[EE + e]], 1);
    ssrc[pos] = ei[e];
}

// ---------------------------------------------------------------------------
// aggregate + fuse: h[node] = bf16((1+eps)*x[node] + sum_{src in CSR} x[src])
// 32 lanes (float4) per node; gather rows hit L3 (x = 51 MB < 256 MB)
// ---------------------------------------------------------------------------
__global__ __launch_bounds__(256) void aggregate_k(
    const float4* __restrict__ x4, const int* __restrict__ ssrc,
    const int* __restrict__ offs, const int* __restrict__ deg,
    const float* __restrict__ epsp, ushort4* __restrict__ hout) {
    int tid = blockIdx.x * 256 + threadIdx.x;
    int node = tid >> 5, lane = tid & 31;
    if (node >= NN) return;
    int start = offs[node], d = deg[node];
    float ef = 1.0f + epsp[0];
    float4 v = x4[node * 32 + lane];
    float4 acc = make_float4(ef * v.x, ef * v.y, ef * v.z, ef * v.w);
    for (int j = 0; j < d; ++j) {
        int s = ssrc[start + j];
        float4 xv = x4[s * 32 + lane];
        acc.x += xv.x; acc.y += xv.y; acc.z += xv.z; acc.w += xv.w;
    }
    ushort4 u;
    u.x = f2bf(acc.x); u.y = f2bf(acc.y); u.z = f2bf(acc.z); u.w = f2bf(acc.w);
    hout[node * 32 + lane] = u;
}

// ---------------------------------------------------------------------------
// fused GEMM + bias + BN-stat accumulation (bf16 input [N,128] row-major)
// y = in @ W^T + b (fp32), stats[c] += col-sum, stats[128+c] += col-sumsq
// ---------------------------------------------------------------------------
__global__ __launch_bounds__(256, 2) void gin_gemm_k(
    const unsigned short* __restrict__ hin,
    const float* __restrict__ W, const float* __restrict__ bias,
    float* __restrict__ y, float* __restrict__ stats) {
    __shared__ __align__(16) unsigned short Ah[128][136];  // +8 pad
    __shared__ __align__(16) unsigned short Bw[128][136];
    __shared__ __align__(16) float s_sum[128];
    __shared__ __align__(16) float s_sq[128];

    const int tid = threadIdx.x;
    const int rowBase = blockIdx.x * 128;

    if (tid < 128) { s_sum[tid] = 0.f; s_sq[tid] = 0.f; }

    // stage W (row-major [out][k]) as bf16; B-fragment row n = W row n
    const float4* W4 = (const float4*)W;
#pragma unroll
    for (int j = 0; j < 16; ++j) {
        int f4 = j * 256 + tid;
        int row = f4 >> 5, k4 = f4 & 31;
        float4 wv = W4[f4];
        ushort4 u;
        u.x = f2bf(wv.x); u.y = f2bf(wv.y); u.z = f2bf(wv.z); u.w = f2bf(wv.w);
        *(ushort4*)&Bw[row][k4 * 4] = u;
    }

    const int4* h16 = (const int4*)hin;
#pragma unroll
    for (int j = 0; j < 8; ++j) {
        int c = j * 256 + tid;
        int row = c >> 4, c8 = c & 15;
        int rg = rowBase + row;
        int4 v = make_int4(0, 0, 0, 0);
        if (rg < NN) v = h16[rg * 16 + c8];
        *(int4*)&Ah[row][c8 * 8] = v;
    }

    __syncthreads();

    const int l = tid & 63, w = tid >> 6;
    const int m = l & 15, q = l >> 4;

    floatx4 acc[2][8];
#pragma unroll
    for (int rt = 0; rt < 2; ++rt)
#pragma unroll
        for (int ct = 0; ct < 8; ++ct) acc[rt][ct] = (floatx4)0.0f;

#pragma unroll
    for (int kc = 0; kc < 4; ++kc) {
        int k0 = kc * 32 + q * 8;
        bf16x8 a0 = *(const bf16x8*)&Ah[w * 32 + m][k0];
        bf16x8 a1 = *(const bf16x8*)&Ah[w * 32 + 16 + m][k0];
#pragma unroll
        for (int ct = 0; ct < 8; ++ct) {
            bf16x8 b = *(const bf16x8*)&Bw[ct * 16 + m][k0];
            acc[0][ct] = __builtin_amdgcn_mfma_f32_16x16x32_bf16(a0, b, acc[0][ct], 0, 0, 0);
            acc[1][ct] = __builtin_amdgcn_mfma_f32_16x16x32_bf16(a1, b, acc[1][ct], 0, 0, 0);
        }
    }

    // epilogue: bias, store y, per-column partial stats (mask padding rows)
#pragma unroll
    for (int ct = 0; ct < 8; ++ct) {
        int col = ct * 16 + m;
        float bc = bias[col];
        float ps = 0.f, pq = 0.f;
#pragma unroll
        for (int rt = 0; rt < 2; ++rt) {
#pragma unroll
            for (int i = 0; i < 4; ++i) {
                int rg = rowBase + w * 32 + rt * 16 + q * 4 + i;
                if (rg < NN) {
                    float yv = acc[rt][ct][i] + bc;
                    y[rg * 128 + col] = yv;
                    ps += yv;
                    pq += yv * yv;
                }
            }
        }
        atomicAdd(&s_sum[col], ps);
        atomicAdd(&s_sq[col], pq);
    }
    __syncthreads();
    if (tid < 128) {
        unsafeAtomicAdd(&stats[tid], s_sum[tid]);
        unsafeAtomicAdd(&stats[128 + tid], s_sq[tid]);
    }
}

// ---------------------------------------------------------------------------
// BN(train, biased var) + ReLU.  OUT_BF16: write bf16 (h1) else fp32 in place
// ---------------------------------------------------------------------------
template <int OUT_BF16>
__global__ __launch_bounds__(256) void bn_relu_k(
    const float* __restrict__ y, const float* __restrict__ stats,
    const float* __restrict__ g, const float* __restrict__ beta,
    float* outf, unsigned short* __restrict__ outh) {
    __shared__ __align__(16) float sc[128];
    __shared__ __align__(16) float sh[128];
    int t = threadIdx.x;
    if (t < 128) {
        const float inv = 1.0f / (float)NN;
        float mean = stats[t] * inv;
        float var = stats[128 + t] * inv - mean * mean;
        float s = g[t] * rsqrtf(var + 1e-5f);
        sc[t] = s;
        sh[t] = beta[t] - mean * s;
    }
    __syncthreads();
    const int total4 = NN * 32;
    const float4* y4 = (const float4*)y;
    for (int i = blockIdx.x * 256 + t; i < total4; i += gridDim.x * 256) {
        int c4 = i & 31;
        float4 v = y4[i];
        float4 s = ((const float4*)sc)[c4];
        float4 b = ((const float4*)sh)[c4];
        float r0 = fmaxf(v.x * s.x + b.x, 0.f);
        float r1 = fmaxf(v.y * s.y + b.y, 0.f);
        float r2 = fmaxf(v.z * s.z + b.z, 0.f);
        float r3 = fmaxf(v.w * s.w + b.w, 0.f);
        if (OUT_BF16) {
            ushort4 u;
            u.x = f2bf(r0); u.y = f2bf(r1); u.z = f2bf(r2); u.w = f2bf(r3);
            ((ushort4*)outh)[i] = u;
        } else {
            ((float4*)outf)[i] = make_float4(r0, r1, r2, r3);
        }
    }
}

// ---------------------------------------------------------------------------
extern "C" void kernel_launch(void* const* d_in, const int* in_sizes, int n_in,
                              void* d_out, int out_size, void* d_ws, size_t ws_size,
                              hipStream_t stream) {
    const float* x   = (const float*)d_in[0];
    const int* ei    = (const int*)d_in[1];   // int64 in ref -> int32 from harness
    // d_in[2] = eps
    const float* W1  = (const float*)d_in[3];
    const float* b1  = (const float*)d_in[4];
    const float* g1  = (const float*)d_in[5];
    const float* be1 = (const float*)d_in[6];
    const float* W2  = (const float*)d_in[7];
    const float* b2  = (const float*)d_in[8];
    const float* g2  = (const float*)d_in[9];
    const float* be2 = (const float*)d_in[10];
    const float* eps = (const float*)d_in[2];
    float* out = (float*)d_out;

    // Workspace layout (~30 MB):
    int* deg        = (int*)d_ws;           // NPAD
    int* offs       = deg + NPAD;           // NPAD
    int* cursor     = offs + NPAD;          // NPAD
    int* chunkSums  = cursor + NPAD;        // 512
    int* ssrc       = chunkSums + 512;      // EE + pad
    unsigned short* hbuf = (unsigned short*)(ssrc + EE + 256);  // N*D bf16
    float* stats    = (float*)(hbuf + (size_t)NN * DD);         // 512

    hipMemsetAsync(deg, 0, NPAD * sizeof(int), stream);
    hipMemsetAsync(stats, 0, 512 * sizeof(float), stream);

    const int numChunks = (NN + 255) / 256;  // 391
    hist_k<<<(EE + 255) / 256, 256, 0, stream>>>(ei, deg);
    scan1_k<<<numChunks, 256, 0, stream>>>(deg, offs, chunkSums);
    scan2_k<<<1, 512, 0, stream>>>(chunkSums, numChunks);
    scan3_k<<<numChunks, 256, 0, stream>>>(offs, chunkSums, cursor);
    esort_k<<<(EE + 255) / 256, 256, 0, stream>>>(ei, cursor, ssrc);
    aggregate_k<<<(NN * 32 + 255) / 256, 256, 0, stream>>>(
        (const float4*)x, ssrc, offs, deg, eps, (ushort4*)hbuf);

    int gblocks = (NN + 127) / 128;  // 782
    gin_gemm_k<<<gblocks, 256, 0, stream>>>(hbuf, W1, b1, out, stats);
    bn_relu_k<1><<<4096, 256, 0, stream>>>(out, stats, g1, be1, nullptr, hbuf);
    gin_gemm_k<<<gblocks, 256, 0, stream>>>(hbuf, W2, b2, out, stats + 256);
    bn_relu_k<0><<<4096, 256, 0, stream>>>(out, stats + 256, g2, be2, out, nullptr);
}